// Round 4
// baseline (107.290 us; speedup 1.0000x reference)
//
#include <hip/hip_runtime.h>
#include <hip/hip_bf16.h>

#define A_TOTAL 34000
#define NBOX 128

// Level layout: [base, count, grid, stride, anchor_size]
// L0: base 0,     25600, G=160, s=4,  a=16
// L1: base 25600,  6400, G=80,  s=8,  a=32
// L2: base 32000,  1600, G=40,  s=16, a=64
// L3: base 33600,   400, G=20,  s=32, a=128

__global__ __launch_bounds__(256) void multi_anchor_encode(
    const float* __restrict__ boxes,   // [B, NBOX, 4] yxyx, f32
    float* __restrict__ out)           // [B, A_TOTAL, 5], f32 (reference output dtype)
{
    __shared__ float4 sbox[NBOX];   // yxyx per box
    __shared__ float  sarea[NBOX];  // (ymax-ymin)*(xmax-xmin)

    const int b = blockIdx.y;
    const int t = threadIdx.x;

    // Stage this batch's boxes into LDS (threads 0..127), precompute areas.
    const float4* bb = reinterpret_cast<const float4*>(boxes + (size_t)b * NBOX * 4);
    if (t < NBOX) {
        float4 v = bb[t];                       // x=ymin y=xmin z=ymax w=xmax
        sbox[t]  = v;
        sarea[t] = __fmul_rn(__fsub_rn(v.z, v.x), __fsub_rn(v.w, v.y));
    }
    __syncthreads();

    const int a = blockIdx.x * 256 + t;
    if (a >= A_TOTAL) return;

    // Decode anchor (cy, cx, size). Faithful to the jax reference:
    // meshgrid(indexing='ij') + row-major reshape => cy = (k/G)*s, cx = (k%G)*s.
    float cy, cx, asize;
    if (a < 25600)      { int k = a;         int i = k / 160, j = k - i * 160; cy = (float)(i * 4);  cx = (float)(j * 4);  asize = 16.0f;  }
    else if (a < 32000) { int k = a - 25600; int i = k / 80,  j = k - i * 80;  cy = (float)(i * 8);  cx = (float)(j * 8);  asize = 32.0f;  }
    else if (a < 33600) { int k = a - 32000; int i = k / 40,  j = k - i * 40;  cy = (float)(i * 16); cx = (float)(j * 16); asize = 64.0f;  }
    else                { int k = a - 33600; int i = k / 20,  j = k - i * 20;  cy = (float)(i * 32); cx = (float)(j * 32); asize = 128.0f; }

    const float half   = asize * 0.5f;     // exact (power of two)
    const float area_a = asize * asize;    // exact
    const float ay0 = cy - half, ax0 = cx - half;  // exact int arithmetic in f32
    const float ay1 = cy + half, ax1 = cx + half;

    // Argmax over 128 boxes. Replicates numpy f32 bit-exactly so near-tie
    // argmax matches the 'np' scoring ref: rn intrinsics block FMA
    // contraction; __fdiv_rn is IEEE correctly-rounded; strict '>' from -1
    // keeps the FIRST max (matches np.argmax, incl. the all-zero-IoU case).
    float best = -1.0f;
    int   bi   = 0;
    #pragma unroll 4
    for (int j = 0; j < NBOX; ++j) {
        float4 v    = sbox[j];                      // wave-uniform broadcast
        float ymin  = fmaxf(ay0, v.x);
        float xmin  = fmaxf(ax0, v.y);
        float ymax  = fminf(ay1, v.z);
        float xmax  = fminf(ax1, v.w);
        float ih    = fmaxf(__fsub_rn(ymax, ymin), 0.0f);
        float iw    = fmaxf(__fsub_rn(xmax, xmin), 0.0f);
        float inter = __fmul_rn(ih, iw);
        float denom = __fsub_rn(__fadd_rn(area_a, sarea[j]), inter);
        float iou   = __fdiv_rn(inter, denom);      // denom >= area_a > 0
        if (iou > best) { best = iou; bi = j; }
    }

    // Matched box -> yxhw, offsets / anchor size (exact power-of-two scale).
    float4 m  = sbox[bi];
    float mcy = __fmul_rn(__fadd_rn(m.x, m.z), 0.5f);
    float mcx = __fmul_rn(__fadd_rn(m.y, m.w), 0.5f);
    float mh  = __fsub_rn(m.z, m.x);
    float mw  = __fsub_rn(m.w, m.y);
    float inv = 1.0f / asize;   // exact (power of two)

    size_t o = ((size_t)b * A_TOTAL + a) * 5;
    out[o + 0] = best;
    out[o + 1] = __fmul_rn(__fsub_rn(mcy, cy), inv);
    out[o + 2] = __fmul_rn(__fsub_rn(mcx, cx), inv);
    out[o + 3] = __fmul_rn(__fsub_rn(mh, asize), inv);
    out[o + 4] = __fmul_rn(__fsub_rn(mw, asize), inv);
}

extern "C" void kernel_launch(void* const* d_in, const int* in_sizes, int n_in,
                              void* d_out, int out_size, void* d_ws, size_t ws_size,
                              hipStream_t stream) {
    const float* boxes = (const float*)d_in[0];
    float* out = (float*)d_out;   // reference output dtype is float32
    dim3 grid((A_TOTAL + 255) / 256, 16 /*B*/);
    multi_anchor_encode<<<grid, 256, 0, stream>>>(boxes, out);
}

// Round 5
// 74.495 us; speedup vs baseline: 1.4402x; 1.4402x over previous
//
#include <hip/hip_runtime.h>

#define NBOX 128
#define A_TOTAL 34000

// Levels (H=W=640): L0 G=160 s=4  a=16  base=0      (25600 anchors, 100 16x16 tiles)
//                   L1 G=80  s=8  a=32  base=25600  ( 6400 anchors,  25 16x16 tiles)
//                   L2 G=40  s=16 a=64  base=32000  ( 1600 anchors,   7 chunks of 256)
//                   L3 G=20  s=32 a=128 base=33600  (  400 anchors,   2 chunks of 256)
// grid.x = 100+25+7+2 = 134 blocks, grid.y = B

__global__ __launch_bounds__(256) void multi_anchor_encode_tiled(
    const float* __restrict__ boxes,   // [B, NBOX, 4] yxyx f32
    float* __restrict__ out)           // [B, A_TOTAL, 5] f32
{
    __shared__ float4 sbox[NBOX];   // all boxes (yxyx)
    __shared__ float  sarea[NBOX];
    __shared__ float4 cbox[NBOX];   // compacted survivors (ascending index order)
    __shared__ float  carea[NBOX];
    __shared__ int    cidx[NBOX];   // survivor -> original box index
    __shared__ int    scount;

    const int b   = blockIdx.y;
    const int t   = threadIdx.x;
    const int bid = blockIdx.x;

    // Stage boxes + areas (bit-exact rn chain, same as verified dense kernel).
    const float4* bb = reinterpret_cast<const float4*>(boxes + (size_t)b * NBOX * 4);
    if (t < NBOX) {
        float4 v = bb[t];                       // x=ymin y=xmin z=ymax w=xmax
        sbox[t]  = v;
        sarea[t] = __fmul_rn(__fsub_rn(v.z, v.x), __fsub_rn(v.w, v.y));
    }
    __syncthreads();

    // Per-thread anchor + per-block conservative tile bounds.
    int   ia = 0, ja = 0, a_flat = 0;
    float s = 4.f, asize = 16.f;
    bool  valid = true;
    float ty0, ty1, tx0, tx1;

    if (bid < 100) {                       // L0: 16x16 tile
        int ty = bid / 10, tx = bid - ty * 10;
        int i0 = ty * 16, j0 = tx * 16;
        ia = i0 + (t >> 4); ja = j0 + (t & 15);
        s = 4.f; asize = 16.f;
        a_flat = ia * 160 + ja;
        ty0 = (float)(i0 * 4 - 8);  ty1 = (float)((i0 + 15) * 4 + 8);
        tx0 = (float)(j0 * 4 - 8);  tx1 = (float)((j0 + 15) * 4 + 8);
    } else if (bid < 125) {                // L1: 16x16 tile
        int q = bid - 100; int ty = q / 5, tx = q - ty * 5;
        int i0 = ty * 16, j0 = tx * 16;
        ia = i0 + (t >> 4); ja = j0 + (t & 15);
        s = 8.f; asize = 32.f;
        a_flat = 25600 + ia * 80 + ja;
        ty0 = (float)(i0 * 8 - 16); ty1 = (float)((i0 + 15) * 8 + 16);
        tx0 = (float)(j0 * 8 - 16); tx1 = (float)((j0 + 15) * 8 + 16);
    } else if (bid < 132) {                // L2: flat chunks of 256 (y-band cull)
        int c = bid - 125; int k = c * 256 + t;
        valid = (k < 1600); int kk = valid ? k : 0;
        ia = kk / 40; ja = kk - ia * 40;
        s = 16.f; asize = 64.f;
        a_flat = 32000 + kk;
        int klo = c * 256, khi = (klo + 255 < 1599) ? klo + 255 : 1599;
        int ilo = klo / 40, ihi = khi / 40;
        ty0 = (float)(ilo * 16 - 32); ty1 = (float)(ihi * 16 + 32);
        tx0 = -1e30f; tx1 = 1e30f;
    } else {                               // L3: flat chunks of 256 (y-band cull)
        int c = bid - 132; int k = c * 256 + t;
        valid = (k < 400); int kk = valid ? k : 0;
        ia = kk / 20; ja = kk - ia * 20;
        s = 32.f; asize = 128.f;
        a_flat = 33600 + kk;
        int klo = c * 256, khi = (klo + 255 < 399) ? klo + 255 : 399;
        int ilo = klo / 20, ihi = khi / 20;
        ty0 = (float)(ilo * 32 - 64); ty1 = (float)(ihi * 32 + 64);
        tx0 = -1e30f; tx1 = 1e30f;
    }

    // Wave 0 builds the ORDERED survivor list (conservative >=/<= tests:
    // a culled box provably has inter == 0 with every anchor in this tile).
    if (t < 64) {
        float4 v0 = sbox[t];
        float4 v1 = sbox[t + 64];
        bool k0 = (v0.z >= ty0) && (v0.x <= ty1) && (v0.w >= tx0) && (v0.y <= tx1);
        bool k1 = (v1.z >= ty0) && (v1.x <= ty1) && (v1.w >= tx0) && (v1.y <= tx1);
        unsigned long long b0 = __ballot(k0);
        unsigned long long b1 = __ballot(k1);
        unsigned long long below = ((unsigned long long)1 << t) - 1ull;
        int n0 = __popcll(b0);
        if (k0) cidx[__popcll(b0 & below)] = t;
        if (k1) cidx[n0 + __popcll(b1 & below)] = t + 64;
        if (t == 0) scount = n0 + __popcll(b1);
    }
    __syncthreads();
    const int cnt = scount;
    if (t < cnt) { int m = cidx[t]; cbox[t] = sbox[m]; carea[t] = sarea[m]; }
    __syncthreads();

    const float half   = asize * 0.5f;
    const float area_a = asize * asize;
    const float cy = (float)ia * s, cx = (float)ja * s;   // exact (ints)
    const float ay0 = cy - half, ax0 = cx - half;
    const float ay1 = cy + half, ax1 = cx + half;

    // Scan survivors in index order. best starts at 0 with bi fallback 0:
    // zero-IoU entries never update (matches np.argmax: all-zero row -> 0;
    // positive max -> first index achieving it, since list is ascending and
    // the rn chain reproduces numpy f32 bit-exactly).
    float best = 0.0f; int bl = 0;
    for (int m = 0; m < cnt; ++m) {
        float4 v   = cbox[m];                    // wave-uniform LDS broadcast
        float ymin = fmaxf(ay0, v.x);
        float xmin = fmaxf(ax0, v.y);
        float ymax = fminf(ay1, v.z);
        float xmax = fminf(ax1, v.w);
        float ih   = fmaxf(__fsub_rn(ymax, ymin), 0.0f);
        float iw   = fmaxf(__fsub_rn(xmax, xmin), 0.0f);
        float inter = __fmul_rn(ih, iw);
        if (inter > 0.0f) {                      // iou==0 can never beat best>=0
            float denom = __fsub_rn(__fadd_rn(area_a, carea[m]), inter);
            float iou   = __fdiv_rn(inter, denom);
            if (iou > best) { best = iou; bl = m; }
        }
    }

    if (!valid) return;
    int bi = (best > 0.0f) ? cidx[bl] : 0;

    float4 mbx = sbox[bi];
    float mcy = __fmul_rn(__fadd_rn(mbx.x, mbx.z), 0.5f);
    float mcx = __fmul_rn(__fadd_rn(mbx.y, mbx.w), 0.5f);
    float mh  = __fsub_rn(mbx.z, mbx.x);
    float mw  = __fsub_rn(mbx.w, mbx.y);
    float inv = 1.0f / asize;                    // exact power of two

    size_t o = ((size_t)b * A_TOTAL + a_flat) * 5;
    out[o + 0] = best;
    out[o + 1] = __fmul_rn(__fsub_rn(mcy, cy), inv);
    out[o + 2] = __fmul_rn(__fsub_rn(mcx, cx), inv);
    out[o + 3] = __fmul_rn(__fsub_rn(mh, asize), inv);
    out[o + 4] = __fmul_rn(__fsub_rn(mw, asize), inv);
}

extern "C" void kernel_launch(void* const* d_in, const int* in_sizes, int n_in,
                              void* d_out, int out_size, void* d_ws, size_t ws_size,
                              hipStream_t stream) {
    const float* boxes = (const float*)d_in[0];
    float* out = (float*)d_out;
    dim3 grid(134, 16 /*B*/);
    multi_anchor_encode_tiled<<<grid, 256, 0, stream>>>(boxes, out);
}

// Round 6
// 71.426 us; speedup vs baseline: 1.5021x; 1.0430x over previous
//
#include <hip/hip_runtime.h>

#define NBOX 128
#define A_TOTAL 34000

// Levels (H=W=640): L0 G=160 s=4  a=16  base=0      (25600 anchors, 100 16x16 tiles)
//                   L1 G=80  s=8  a=32  base=25600  ( 6400 anchors,  25 16x16 tiles)
//                   L2 G=40  s=16 a=64  base=32000  ( 1600 anchors,   7 chunks of 256)
//                   L3 G=20  s=32 a=128 base=33600  (  400 anchors,   2 chunks of 256)
// grid.x = 100+25+7+2 = 134 blocks, grid.y = B

__global__ __launch_bounds__(256) void multi_anchor_encode_masked(
    const float* __restrict__ boxes,   // [B, NBOX, 4] yxyx f32
    float* __restrict__ out)           // [B, A_TOTAL, 5] f32
{
    __shared__ float4 sbox[NBOX];
    __shared__ float  sarea[NBOX];
    __shared__ unsigned int smask[4];   // survivor bitmask, box j -> bit (j&31) of word (j>>5)

    const int b   = blockIdx.y;
    const int t   = threadIdx.x;
    const int bid = blockIdx.x;

    // ---- Per-thread anchor + per-block conservative tile bounds (no LDS yet).
    int   ia = 0, ja = 0, a_flat = 0;
    float s = 4.f, asize = 16.f;
    bool  valid = true;
    float ty0, ty1, tx0, tx1;

    if (bid < 100) {                       // L0: 16x16 tile
        int ty = bid / 10, tx = bid - ty * 10;
        int i0 = ty * 16, j0 = tx * 16;
        ia = i0 + (t >> 4); ja = j0 + (t & 15);
        s = 4.f; asize = 16.f;
        a_flat = ia * 160 + ja;
        ty0 = (float)(i0 * 4 - 8);  ty1 = (float)((i0 + 15) * 4 + 8);
        tx0 = (float)(j0 * 4 - 8);  tx1 = (float)((j0 + 15) * 4 + 8);
    } else if (bid < 125) {                // L1: 16x16 tile
        int q = bid - 100; int ty = q / 5, tx = q - ty * 5;
        int i0 = ty * 16, j0 = tx * 16;
        ia = i0 + (t >> 4); ja = j0 + (t & 15);
        s = 8.f; asize = 32.f;
        a_flat = 25600 + ia * 80 + ja;
        ty0 = (float)(i0 * 8 - 16); ty1 = (float)((i0 + 15) * 8 + 16);
        tx0 = (float)(j0 * 8 - 16); tx1 = (float)((j0 + 15) * 8 + 16);
    } else if (bid < 132) {                // L2: flat chunks of 256 (y-band cull)
        int c = bid - 125; int k = c * 256 + t;
        valid = (k < 1600); int kk = valid ? k : 0;
        ia = kk / 40; ja = kk - ia * 40;
        s = 16.f; asize = 64.f;
        a_flat = 32000 + kk;
        int klo = c * 256, khi = (klo + 255 < 1599) ? klo + 255 : 1599;
        int ilo = klo / 40, ihi = khi / 40;
        ty0 = (float)(ilo * 16 - 32); ty1 = (float)(ihi * 16 + 32);
        tx0 = -1e30f; tx1 = 1e30f;
    } else {                               // L3: flat chunks of 256 (y-band cull)
        int c = bid - 132; int k = c * 256 + t;
        valid = (k < 400); int kk = valid ? k : 0;
        ia = kk / 20; ja = kk - ia * 20;
        s = 32.f; asize = 128.f;
        a_flat = 33600 + kk;
        int klo = c * 256, khi = (klo + 255 < 399) ? klo + 255 : 399;
        int ilo = klo / 20, ihi = khi / 20;
        ty0 = (float)(ilo * 32 - 64); ty1 = (float)(ihi * 32 + 64);
        tx0 = -1e30f; tx1 = 1e30f;
    }

    // ---- Stage boxes + cull in one pass (waves 0-1 hold box t in registers),
    // ballot builds the ordered survivor bitmask. Conservative >=/<= tests:
    // a culled box provably has inter == 0 with every anchor of this tile.
    const float4* bb = reinterpret_cast<const float4*>(boxes + (size_t)b * NBOX * 4);
    if (t < NBOX) {                        // wave-uniform (waves 0,1 in; 2,3 out)
        float4 v = bb[t];                  // x=ymin y=xmin z=ymax w=xmax
        sbox[t]  = v;
        sarea[t] = __fmul_rn(__fsub_rn(v.z, v.x), __fsub_rn(v.w, v.y));
        bool keep = (v.z >= ty0) && (v.x <= ty1) && (v.w >= tx0) && (v.y <= tx1);
        unsigned long long bm = __ballot(keep);
        if ((t & 63) == 0) {               // lane 0 of each wave
            smask[(t >> 5) + 0] = (unsigned int)bm;
            smask[(t >> 5) + 1] = (unsigned int)(bm >> 32);
        }
    }
    __syncthreads();                       // the ONLY barrier

    const float half   = asize * 0.5f;     // exact (power of two)
    const float area_a = asize * asize;    // exact
    const float cy = (float)ia * s, cx = (float)ja * s;  // exact ints in f32
    const float ay0 = cy - half, ax0 = cx - half;
    const float ay1 = cy + half, ax1 = cx + half;

    // ---- Ordered survivor walk. best=0 / bi=0 matches np.argmax semantics
    // (all-zero row -> index 0; else first index attaining the max, since j
    // ascends and the accept-path rn chain is bit-identical to numpy f32).
    // Division filter: iou>best requires inter > best*denom*(1-2^-23); the
    // 0.9999995 factor is strictly looser, so skips are provably safe.
    float best = 0.0f; int bi = 0;
    #pragma unroll
    for (int w = 0; w < 4; ++w) {
        unsigned int m = (unsigned int)__builtin_amdgcn_readfirstlane(smask[w]);
        const int jb = w << 5;
        while (m) {
            int j = jb + __builtin_ctz(m);
            m &= m - 1;
            float4 v  = sbox[j];           // wave-uniform LDS broadcast
            float sa  = sarea[j];
            float ymin = fmaxf(ay0, v.x);
            float xmin = fmaxf(ax0, v.y);
            float ymax = fminf(ay1, v.z);
            float xmax = fminf(ax1, v.w);
            float ih   = fmaxf(__fsub_rn(ymax, ymin), 0.0f);
            float iw   = fmaxf(__fsub_rn(xmax, xmin), 0.0f);
            float inter = __fmul_rn(ih, iw);
            float denom = __fsub_rn(__fadd_rn(area_a, sa), inter);
            float thr   = __fmul_rn(__fmul_rn(best, denom), 0.9999995f);
            if (inter > thr) {
                float iou = __fdiv_rn(inter, denom);   // IEEE, == numpy f32
                if (iou > best) { best = iou; bi = j; }
            }
        }
    }

    if (!valid) return;

    float4 mbx = sbox[bi];
    float mcy = __fmul_rn(__fadd_rn(mbx.x, mbx.z), 0.5f);
    float mcx = __fmul_rn(__fadd_rn(mbx.y, mbx.w), 0.5f);
    float mh  = __fsub_rn(mbx.z, mbx.x);
    float mw  = __fsub_rn(mbx.w, mbx.y);
    float inv = 1.0f / asize;              // exact power of two

    size_t o = ((size_t)b * A_TOTAL + a_flat) * 5;
    out[o + 0] = best;
    out[o + 1] = __fmul_rn(__fsub_rn(mcy, cy), inv);
    out[o + 2] = __fmul_rn(__fsub_rn(mcx, cx), inv);
    out[o + 3] = __fmul_rn(__fsub_rn(mh, asize), inv);
    out[o + 4] = __fmul_rn(__fsub_rn(mw, asize), inv);
}

extern "C" void kernel_launch(void* const* d_in, const int* in_sizes, int n_in,
                              void* d_out, int out_size, void* d_ws, size_t ws_size,
                              hipStream_t stream) {
    const float* boxes = (const float*)d_in[0];
    float* out = (float*)d_out;
    dim3 grid(134, 16 /*B*/);
    multi_anchor_encode_masked<<<grid, 256, 0, stream>>>(boxes, out);
}